// Round 2
// baseline (65.226 us; speedup 1.0000x reference)
//
#include <hip/hip_runtime.h>
#include <hip/hip_bf16.h>

typedef float f32x4 __attribute__((ext_vector_type(4)));

namespace {
constexpr int kB = 4;
constexpr int kT = 4096;
constexpr int kC = 8;
constexpr int kN = kB * kT;                           // 16384 tokens
constexpr int kTRows = 16;                            // t-rows per block
constexpr int kSPerThread = 4;                        // s-cols per thread (float4 store)
constexpr int kBlockThreads = 256;
constexpr int kSTile = kBlockThreads * kSPerThread;   // 1024 s-cols per block
}

// Kernel 1: per token -> softmax probs p[8] and z = Cmat * p (so the bilinear
// form becomes a plain dot8 in the main kernel).
__global__ __launch_bounds__(256) void dam_prep(const int* __restrict__ token_ids,
                                                const float* __restrict__ emb,
                                                const float* __restrict__ cmat,
                                                float* __restrict__ p_ws,
                                                float* __restrict__ z_ws) {
    int tid = blockIdx.x * blockDim.x + threadIdx.x;
    if (tid >= kN) return;
    int tok = token_ids[tid];
    const f32x4* row = reinterpret_cast<const f32x4*>(emb) + (size_t)tok * 2;
    f32x4 e0 = row[0], e1 = row[1];
    float e[kC] = {e0.x, e0.y, e0.z, e0.w, e1.x, e1.y, e1.z, e1.w};
    float m = e[0];
#pragma unroll
    for (int i = 1; i < kC; ++i) m = fmaxf(m, e[i]);
    float p[kC], sum = 0.f;
#pragma unroll
    for (int i = 0; i < kC; ++i) { p[i] = __expf(e[i] - m); sum += p[i]; }
    float inv = 1.0f / sum;
#pragma unroll
    for (int i = 0; i < kC; ++i) p[i] *= inv;
    // z[c] = sum_d Cmat[c][d] * p[d]
    float z[kC];
#pragma unroll
    for (int c = 0; c < kC; ++c) {
        float acc = 0.f;
#pragma unroll
        for (int d = 0; d < kC; ++d) acc = fmaf(cmat[c * kC + d], p[d], acc);
        z[c] = acc;
    }
    f32x4* po = reinterpret_cast<f32x4*>(p_ws) + (size_t)tid * 2;
    po[0] = f32x4{p[0], p[1], p[2], p[3]};
    po[1] = f32x4{p[4], p[5], p[6], p[7]};
    f32x4* zo = reinterpret_cast<f32x4*>(z_ws) + (size_t)tid * 2;
    zo[0] = f32x4{z[0], z[1], z[2], z[3]};
    zo[1] = f32x4{z[4], z[5], z[6], z[7]};
}

// Kernel 2: out[b,t,s] = 2*sigmoid(dot8(p[b,t], z[b,s])) - 1
// Tile: kTRows t-rows x kSTile s-cols per 256-thread block.
// p rows broadcast from LDS (uniform address -> no bank conflict);
// z rows per-thread in registers, reused across the 16 t-rows.
__global__ __launch_bounds__(256) void dam_mask(const float* __restrict__ p_ws,
                                                const float* __restrict__ z_ws,
                                                float* __restrict__ out) {
    const int b = blockIdx.z;
    const int t0 = blockIdx.y * kTRows;
    const int s0 = blockIdx.x * kSTile;
    __shared__ float p_lds[kTRows * kC];
    const int tid = threadIdx.x;
    if (tid < kTRows * kC)
        p_lds[tid] = p_ws[((size_t)(b * kT + t0)) * kC + tid];
    __syncthreads();

    const int s = s0 + tid * kSPerThread;
    const f32x4* zr = reinterpret_cast<const f32x4*>(z_ws) + ((size_t)(b * kT) + s) * 2;
    float z[kSPerThread][kC];
#pragma unroll
    for (int j = 0; j < kSPerThread; ++j) {
        f32x4 a = zr[j * 2 + 0];
        f32x4 c = zr[j * 2 + 1];
        z[j][0] = a.x; z[j][1] = a.y; z[j][2] = a.z; z[j][3] = a.w;
        z[j][4] = c.x; z[j][5] = c.y; z[j][6] = c.z; z[j][7] = c.w;
    }

    float* orow = out + ((size_t)(b * kT + t0)) * kT + s;
#pragma unroll
    for (int tt = 0; tt < kTRows; ++tt) {
        float pr[kC];
#pragma unroll
        for (int i = 0; i < kC; ++i) pr[i] = p_lds[tt * kC + i];
        float r[kSPerThread];
#pragma unroll
        for (int j = 0; j < kSPerThread; ++j) {
            float acc = 0.f;
#pragma unroll
            for (int i = 0; i < kC; ++i) acc = fmaf(pr[i], z[j][i], acc);
            // 2*sigmoid(x)-1 = (1 - e^-x) / (1 + e^-x)
            float ex = __expf(-acc);
            r[j] = (1.f - ex) * __builtin_amdgcn_rcpf(1.f + ex);
        }
        f32x4 ov = {r[0], r[1], r[2], r[3]};
        __builtin_nontemporal_store(ov, reinterpret_cast<f32x4*>(orow + (size_t)tt * kT));
    }
}

extern "C" void kernel_launch(void* const* d_in, const int* in_sizes, int n_in,
                              void* d_out, int out_size, void* d_ws, size_t ws_size,
                              hipStream_t stream) {
    const int* token_ids = (const int*)d_in[0];
    const float* emb     = (const float*)d_in[1];
    const float* cmat    = (const float*)d_in[2];
    float* out  = (float*)d_out;
    float* p_ws = (float*)d_ws;                      // kN*8 floats
    float* z_ws = p_ws + (size_t)kN * kC;            // kN*8 floats (total 1 MB)

    dam_prep<<<(kN + 255) / 256, 256, 0, stream>>>(token_ids, emb, cmat, p_ws, z_ws);
    dim3 grid(kT / kSTile, kT / kTRows, kB);         // (4, 256, 4)
    dam_mask<<<grid, kBlockThreads, 0, stream>>>(p_ws, z_ws, out);
}

// Round 3
// 53.387 us; speedup vs baseline: 1.2218x; 1.2218x over previous
//
#include <hip/hip_runtime.h>
#include <hip/hip_bf16.h>

typedef float f32x4 __attribute__((ext_vector_type(4)));

namespace {
constexpr int kB = 4;
constexpr int kT = 4096;
constexpr int kC = 8;
constexpr int kN = kB * kT;                           // 16384 tokens
constexpr int kTRows = 16;                            // t-rows per block
constexpr int kSPerThread = 4;                        // s-cols per thread (float4 store)
constexpr int kBlockThreads = 256;
constexpr int kSTile = kBlockThreads * kSPerThread;   // 1024 s-cols per block
}

// Kernel 1: per token -> softmax probs p[8] and z = -(Cmat * p)  (negated so
// the main kernel's sigmoid argument exp(-x) folds into the FMA chain).
__global__ __launch_bounds__(256) void dam_prep(const int* __restrict__ token_ids,
                                                const float* __restrict__ emb,
                                                const float* __restrict__ cmat,
                                                float* __restrict__ p_ws,
                                                float* __restrict__ z_ws) {
    int tid = blockIdx.x * blockDim.x + threadIdx.x;
    if (tid >= kN) return;
    int tok = token_ids[tid];
    const f32x4* row = reinterpret_cast<const f32x4*>(emb) + (size_t)tok * 2;
    f32x4 e0 = row[0], e1 = row[1];
    float e[kC] = {e0.x, e0.y, e0.z, e0.w, e1.x, e1.y, e1.z, e1.w};
    float m = e[0];
#pragma unroll
    for (int i = 1; i < kC; ++i) m = fmaxf(m, e[i]);
    float p[kC], sum = 0.f;
#pragma unroll
    for (int i = 0; i < kC; ++i) { p[i] = __expf(e[i] - m); sum += p[i]; }
    float inv = 1.0f / sum;
#pragma unroll
    for (int i = 0; i < kC; ++i) p[i] *= inv;
    // z[c] = -sum_d Cmat[c][d] * p[d]   (note the negation)
    float z[kC];
#pragma unroll
    for (int c = 0; c < kC; ++c) {
        float acc = 0.f;
#pragma unroll
        for (int d = 0; d < kC; ++d) acc = fmaf(cmat[c * kC + d], p[d], acc);
        z[c] = -acc;
    }
    f32x4* po = reinterpret_cast<f32x4*>(p_ws) + (size_t)tid * 2;
    po[0] = f32x4{p[0], p[1], p[2], p[3]};
    po[1] = f32x4{p[4], p[5], p[6], p[7]};
    f32x4* zo = reinterpret_cast<f32x4*>(z_ws) + (size_t)tid * 2;
    zo[0] = f32x4{z[0], z[1], z[2], z[3]};
    zo[1] = f32x4{z[4], z[5], z[6], z[7]};
}

// Kernel 2: out[b,t,s] = 2*sigmoid(dot8(p[b,t], -z_neg[b,s])) - 1
//         = (1 - e^x)/(1 + e^x) with x = dot8(p, z_neg)
// Tile: kTRows t-rows x kSTile s-cols per 256-thread block.
// p rows broadcast from LDS via ds_read_b128 (uniform addr -> broadcast);
// z rows per-thread in registers, reused across the 16 t-rows.
__global__ __launch_bounds__(256) void dam_mask(const float* __restrict__ p_ws,
                                                const float* __restrict__ z_ws,
                                                float* __restrict__ out) {
    const int b = blockIdx.z;
    const int t0 = blockIdx.y * kTRows;
    const int s0 = blockIdx.x * kSTile;
    __shared__ f32x4 p_lds[kTRows * 2];   // 16 rows x 8 floats, as f32x4 pairs
    const int tid = threadIdx.x;
    if (tid < kTRows * 2)
        p_lds[tid] = reinterpret_cast<const f32x4*>(p_ws + ((size_t)(b * kT + t0)) * kC)[tid];
    __syncthreads();

    const int s = s0 + tid * kSPerThread;
    const f32x4* zr = reinterpret_cast<const f32x4*>(z_ws) + ((size_t)(b * kT) + s) * 2;
    float z[kSPerThread][kC];
#pragma unroll
    for (int j = 0; j < kSPerThread; ++j) {
        f32x4 a = zr[j * 2 + 0];
        f32x4 c = zr[j * 2 + 1];
        z[j][0] = a.x; z[j][1] = a.y; z[j][2] = a.z; z[j][3] = a.w;
        z[j][4] = c.x; z[j][5] = c.y; z[j][6] = c.z; z[j][7] = c.w;
    }

    float* orow = out + ((size_t)(b * kT + t0)) * kT + s;
#pragma unroll
    for (int tt = 0; tt < kTRows; ++tt) {
        f32x4 p0 = p_lds[tt * 2 + 0];
        f32x4 p1 = p_lds[tt * 2 + 1];
        float pr[kC] = {p0.x, p0.y, p0.z, p0.w, p1.x, p1.y, p1.z, p1.w};
        float r[kSPerThread];
#pragma unroll
        for (int j = 0; j < kSPerThread; ++j) {
            float acc = 0.f;   // acc = -compat
#pragma unroll
            for (int i = 0; i < kC; ++i) acc = fmaf(pr[i], z[j][i], acc);
            // 2*sigmoid(-acc)-1 = (1 - e^acc) / (1 + e^acc)
            float ex = __expf(acc);
            r[j] = (1.f - ex) * __builtin_amdgcn_rcpf(1.f + ex);
        }
        f32x4 ov = {r[0], r[1], r[2], r[3]};
        *reinterpret_cast<f32x4*>(orow + (size_t)tt * kT) = ov;
    }
}

extern "C" void kernel_launch(void* const* d_in, const int* in_sizes, int n_in,
                              void* d_out, int out_size, void* d_ws, size_t ws_size,
                              hipStream_t stream) {
    const int* token_ids = (const int*)d_in[0];
    const float* emb     = (const float*)d_in[1];
    const float* cmat    = (const float*)d_in[2];
    float* out  = (float*)d_out;
    float* p_ws = (float*)d_ws;                      // kN*8 floats
    float* z_ws = p_ws + (size_t)kN * kC;            // kN*8 floats (total 1 MB)

    dam_prep<<<(kN + 255) / 256, 256, 0, stream>>>(token_ids, emb, cmat, p_ws, z_ws);
    dim3 grid(kT / kSTile, kT / kTRows, kB);         // (4, 256, 4)
    dam_mask<<<grid, kBlockThreads, 0, stream>>>(p_ws, z_ws, out);
}